// Round 8
// baseline (177.925 us; speedup 1.0000x reference)
//
#include <hip/hip_runtime.h>

typedef unsigned short u16;
typedef __attribute__((ext_vector_type(8))) short bf16x8;
typedef __attribute__((ext_vector_type(4))) short s16x4;
typedef __attribute__((ext_vector_type(4))) float f32x4;

#define MFMA(a, b, c) __builtin_amdgcn_mfma_f32_16x16x32_bf16(a, b, c, 0, 0, 0)

// global -> LDS direct copy, 16 B per lane. LDS dest must be wave-uniform base
// (HW adds lane*16). Global source is per-lane.
#define GLDS16(gp, lp)                                                        \
  __builtin_amdgcn_global_load_lds(                                          \
      (__attribute__((address_space(1))) void*)(void*)(gp),                  \
      (__attribute__((address_space(3))) void*)(lp), 16, 0, 0)

__device__ __forceinline__ u16 f2b(float f) {
  union { float f; unsigned u; } x; x.f = f;
  unsigned r = x.u + 0x7fffu + ((x.u >> 16) & 1u);
  return (u16)(r >> 16);
}
__device__ __forceinline__ float b2f(u16 v) {
  union { unsigned u; float f; } x; x.u = ((unsigned)v) << 16;
  return x.f;
}

// Stage a [32*NPASS rows][64 cols] bf16 tile into LDS with XOR-swizzled SOURCE
// slots so a swizzled ds_read recovers linear data. (256-thread version.)
template <int NPASS>
__device__ __forceinline__ void stage64(const u16* __restrict__ src, int ld,
                                        u16* lds, int t) {
  int wave = t >> 6;
#pragma unroll
  for (int p = 0; p < NPASS; ++p) {
    int row = p * 32 + (t >> 3);
    int ss = (t & 7) ^ (row & 7);
    const u16* g = src + row * ld + ss * 8;
    GLDS16(g, lds + (p * 2048 + wave * 512));
  }
}

// 512-thread version: one pass stages a full 64x64 bf16 tile.
__device__ __forceinline__ void stage512(const u16* __restrict__ src, int ld,
                                         u16* lds, int t) {
  int row = t >> 3;
  int ss = (t & 7) ^ (row & 7);
  GLDS16(src + row * ld + ss * 8, lds + (t >> 6) * 512);
}

// read one MFMA fragment (8 consecutive bf16) at [row][slot*8], swizzle-corrected
__device__ __forceinline__ bf16x8 ldsfrag(const u16* base, int row, int slot) {
  int byte = row * 128 + (((slot) ^ (row & 7)) << 4);
  return *(const bf16x8*)((const char*)base + byte);
}

// ---------------------------------------------------------------- prep kernels
__global__ void cast_x_kernel(const float* __restrict__ in, u16* __restrict__ out,
                              int n4) {
  int i = blockIdx.x * blockDim.x + threadIdx.x;
  if (i < n4) {
    float4 v = ((const float4*)in)[i];
    ushort4 o;
    o.x = f2b(v.x); o.y = f2b(v.y); o.z = f2b(v.z); o.w = f2b(v.w);
    ((ushort4*)out)[i] = o;
  }
}

// out[(c, r)] = bf16(in[(r, c)]); in is (R, Ccols) fp32 row-major.
__global__ void transpose_cast(const float* __restrict__ in, u16* __restrict__ out,
                               int R, int Ccols) {
  __shared__ u16 tile[32][33];
  int c0 = blockIdx.x * 32, r0 = blockIdx.y * 32;
  int tx = threadIdx.x & 31, ty = threadIdx.x >> 5;
#pragma unroll
  for (int rr = ty; rr < 32; rr += 8)
    tile[rr][tx] = f2b(in[(size_t)(r0 + rr) * Ccols + c0 + tx]);
  __syncthreads();
#pragma unroll
  for (int rr = ty; rr < 32; rr += 8)
    out[(size_t)(c0 + rr) * R + r0 + tx] = tile[tx][rr];
}

// bias_table (65025,12) fp32 -> per-head contiguous bf16 [12][4096] (3969 used)
__global__ void gather_bias(const float* __restrict__ btab, u16* __restrict__ out) {
  int i = blockIdx.x * 256 + threadIdx.x;  // [0, 12*4096)
  int h = i >> 12, r = i & 4095;
  out[i] = (r < 3969) ? f2b(btab[r * 12 + h]) : (u16)0;
}

// ---------------------------------------------------------------- GEMM 128x128
// C = A(M,K) @ BT(N,K)^T, bf16 inputs, fp32 accum.
template <int EPI>
__global__ __launch_bounds__(256, 2) void gemm128(
    const u16* __restrict__ A, const u16* __restrict__ BT, int K,
    u16* __restrict__ qo, u16* __restrict__ ko, u16* __restrict__ vo,
    const float* __restrict__ pb, float* __restrict__ out, int Nld) {
  __shared__ __align__(16) u16 As[128 * 64];
  __shared__ __align__(16) u16 Bs[128 * 64];
  const int t = threadIdx.x;
  const int wave = t >> 6, lane = t & 63;
  const int wr = wave >> 1, wc = wave & 1;
  const int tileRow = blockIdx.y * 128, tileCol = blockIdx.x * 128;
  const u16* Ab = A + (size_t)tileRow * K;
  const u16* Bb = BT + (size_t)tileCol * K;

  f32x4 acc[4][4] = {};
  for (int k0 = 0; k0 < K; k0 += 64) {
    __syncthreads();
    stage64<4>(Ab + k0, K, As, t);
    stage64<4>(Bb + k0, K, Bs, t);
    __syncthreads();
#pragma unroll
    for (int kk = 0; kk < 2; ++kk) {
      bf16x8 af[4], bfr[4];
#pragma unroll
      for (int m = 0; m < 4; ++m)
        af[m] = ldsfrag(As, wr * 64 + m * 16 + (lane & 15), kk * 4 + (lane >> 4));
#pragma unroll
      for (int n = 0; n < 4; ++n)
        bfr[n] = ldsfrag(Bs, wc * 64 + n * 16 + (lane & 15), kk * 4 + (lane >> 4));
#pragma unroll
      for (int m = 0; m < 4; ++m)
#pragma unroll
        for (int n = 0; n < 4; ++n)
          acc[m][n] = MFMA(af[m], bfr[n], acc[m][n]);
    }
  }

#pragma unroll
  for (int m = 0; m < 4; ++m) {
#pragma unroll
    for (int n = 0; n < 4; ++n) {
#pragma unroll
      for (int r = 0; r < 4; ++r) {
        int row = tileRow + wr * 64 + m * 16 + (lane >> 4) * 4 + r;
        int col = tileCol + wc * 64 + n * 16 + (lane & 15);
        float val = acc[m][n][r];
        if (EPI == 0) {
          int which = col / 768;
          int c = col - which * 768;
          int hh = c >> 6, d = c & 63;
          int bb = row >> 10, nn = row & 1023;
          size_t bhnd = ((size_t)(bb * 12 + hh) * 1024 + nn) * 64 + d;
          if (which == 0)
            qo[bhnd] = f2b(val * 0.125f);
          else if (which == 1)
            ko[bhnd] = f2b(val);
          else
            vo[((size_t)(bb * 12 + hh) * 64 + d) * 1024 + nn] = f2b(val);
        } else {
          out[(size_t)row * Nld + col] = val + pb[col];
        }
      }
    }
  }
}

// ---------------------------------------------------------------- attention
// 8-wave blocks (QBLK=128), swapped-QK softmax, and a T3-minimum pipeline:
// double-buffered K/V staged via global_load_lds with RAW s_barrier + counted
// vmcnt (NOT __syncthreads, whose implicit vmcnt(0) defeats prefetch). Next
// tile's loads fly during the current tile's compute.
// grid: 768 flat (XCD-chunked: one batch per XCD); block: 512 (8 waves).
__global__ __launch_bounds__(512, 6) void attn_kernel(
    const u16* __restrict__ qm, const u16* __restrict__ kmat,
    const u16* __restrict__ vT, const u16* __restrict__ bias_g,
    u16* __restrict__ ao) {
  __shared__ __align__(16) u16 bias_s[35 * 64];
  __shared__ __align__(16) u16 Ks[2][64 * 64];
  __shared__ __align__(16) u16 Vs[2][64 * 64];
  __shared__ __align__(16) u16 Ps[8][1024];  // per-wave 16x64 P tile

  const int t = threadIdx.x;
  const int wave = t >> 6, lane = t & 63;
  const int g = lane >> 4, q = lane & 15;
  // XCD-chunked swizzle: id%8 = XCD, one batch (96 blocks) per XCD.
  const int id = blockIdx.x;
  const int sw = (id & 7) * 96 + (id >> 3);
  const int qt = sw & 7, h = (sw >> 3) % 12, b = sw / 96;
  const int bh = b * 12 + h;

  const u16* kb0 = kmat + (size_t)bh * 1024 * 64;
  const u16* vb0 = vT + (size_t)bh * 64 * 1024;

  // prologue: bias rows dy in [4qt, 4qt+34] (63 cols, stride-64 pad) + tile 0
  if (t < 280) {
    const u16* bg = bias_g + h * 4096 + qt * 4 * 63;
    GLDS16(bg + (t >> 3) * 63 + (t & 7) * 8, bias_s + (t >> 6) * 512);
  }
  stage512(kb0, 64, Ks[0], t);
  stage512(vb0, 1024, Vs[0], t);

  // Q fragments in registers (q pre-scaled by 0.125); B-operand: col = q
  const u16* qb = qm + ((size_t)bh * 1024 + qt * 128) * 64;
  bf16x8 qf[2];
#pragma unroll
  for (int kk = 0; kk < 2; ++kk)
    qf[kk] = *(const bf16x8*)(qb + (wave * 16 + q) * 64 + kk * 32 + g * 8);

  f32x4 o[4] = {};
  float mrun = -1e30f, lrun = 0.f;

  // this lane's softmax q-row (for S^T layout)
  const int iq = qt * 128 + wave * 16 + q;
  const int ylq = (wave * 16 + q) >> 5;  // local yi (0..3): yi = 4qt + ylq
  const int xi = iq & 31;

  int cur = 0;
  for (int kt = 0; kt < 16; ++kt) {
    // barrier#1: every wave has finished READING buf cur^1 (prev iter) --
    // safe to overwrite it with the next tile's DMA.
    __builtin_amdgcn_s_barrier();
    if (kt < 15) {
      stage512(kb0 + (kt + 1) * 64 * 64, 64, Ks[cur ^ 1], t);
      stage512(vb0 + (kt + 1) * 64, 1024, Vs[cur ^ 1], t);
      // wait only for THIS tile's loads (issued one iter ago); the 2 just
      // issued stay in flight across the barrier.
      asm volatile("s_waitcnt vmcnt(2)" ::: "memory");
    } else {
      asm volatile("s_waitcnt vmcnt(0)" ::: "memory");
    }
    // barrier#2: all waves' tile-kt loads have landed -> buf[cur] readable.
    __builtin_amdgcn_s_barrier();

    const u16* Kc = Ks[cur];
    const u16* Vc = Vs[cur];

    // S^T = K @ Q^T: s[n][r] = S[key = n*16 + g*4 + r][qrow = q]
    f32x4 s[4] = {};
#pragma unroll
    for (int kk = 0; kk < 2; ++kk) {
#pragma unroll
      for (int n = 0; n < 4; ++n) {
        bf16x8 kf = ldsfrag(Kc, n * 16 + q, kk * 4 + g);
        s[n] = MFMA(kf, qf[kk], s[n]);
      }
    }

    // + relative position bias: key j = kt*64 + n*16 + g*4 + r
    // local dy row = ylq - kt*2 - (n>>1) + 31; dx descending in r
#pragma unroll
    for (int n = 0; n < 4; ++n) {
      int xj0 = (n & 1) * 16 + g * 4;
      int ldy = ylq - kt * 2 - (n >> 1) + 31;
      int bse = ldy * 64 + (xi - xj0 + 31);
#pragma unroll
      for (int r = 0; r < 4; ++r) s[n][r] += b2f(bias_s[bse - r]);
    }

    // row max: 15 local fmax + 2 cross-group shuffles
    float mx = fmaxf(fmaxf(fmaxf(s[0][0], s[0][1]), fmaxf(s[0][2], s[0][3])),
                     fmaxf(fmaxf(s[1][0], s[1][1]), fmaxf(s[1][2], s[1][3])));
    mx = fmaxf(mx,
               fmaxf(fmaxf(fmaxf(s[2][0], s[2][1]), fmaxf(s[2][2], s[2][3])),
                     fmaxf(fmaxf(s[3][0], s[3][1]), fmaxf(s[3][2], s[3][3]))));
    mx = fmaxf(mx, __shfl_xor(mx, 16));
    mx = fmaxf(mx, __shfl_xor(mx, 32));

    // defer-max (THR=8)
    if (__any(mx > mrun + 8.f)) {
      float mn = fmaxf(mrun, mx);
      float al = __expf(mrun - mn);
      mrun = mn;
      lrun *= al;
#pragma unroll
      for (int r = 0; r < 4; ++r) {
        float ar = __shfl(al, (lane & 48) | (g * 4 + r));
#pragma unroll
        for (int nd = 0; nd < 4; ++nd) o[nd][r] *= ar;
      }
    }

    // exp + sum
    float ps = 0.f;
#pragma unroll
    for (int n = 0; n < 4; ++n) {
#pragma unroll
      for (int r = 0; r < 4; ++r) {
        float p = __expf(s[n][r] - mrun);
        s[n][r] = p;
        ps += p;
      }
    }
    ps += __shfl_xor(ps, 16);
    ps += __shfl_xor(ps, 32);
    lrun += ps;

    // P -> wave-local LDS (row q, keys n*16+g*4..+3), swizzled, short4 stores
#pragma unroll
    for (int n = 0; n < 4; ++n) {
      int byte = (q * 128 + n * 32 + g * 8) ^ ((q & 7) << 4);
      union { unsigned u[2]; s16x4 v; } w;
      w.u[0] = (unsigned)f2b(s[n][0]) | ((unsigned)f2b(s[n][1]) << 16);
      w.u[1] = (unsigned)f2b(s[n][2]) | ((unsigned)f2b(s[n][3]) << 16);
      *(s16x4*)((char*)Ps[wave] + byte) = w.v;
    }
    __builtin_amdgcn_sched_barrier(0);  // fence: P stores before PV reads

    // O += P @ V (A-frag: row q; Vs holds V^T: rows = d, cols = key)
#pragma unroll
    for (int kk = 0; kk < 2; ++kk) {
      bf16x8 pf = ldsfrag(Ps[wave], q, kk * 4 + g);
#pragma unroll
      for (int nd = 0; nd < 4; ++nd) {
        bf16x8 vf = ldsfrag(Vc, nd * 16 + q, kk * 4 + g);
        o[nd] = MFMA(pf, vf, o[nd]);
      }
    }
    cur ^= 1;
  }

  // epilogue: redistribute 1/l to output rows, O/l -> (B, N, nh*hd) bf16
  float lr[4];
#pragma unroll
  for (int r = 0; r < 4; ++r)
    lr[r] = __shfl(lrun, (lane & 48) | (g * 4 + r));
#pragma unroll
  for (int nd = 0; nd < 4; ++nd) {
#pragma unroll
    for (int r = 0; r < 4; ++r) {
      int i = qt * 128 + wave * 16 + g * 4 + r;
      int d = nd * 16 + q;
      float val = o[nd][r] / lr[r];
      ao[((size_t)b * 1024 + i) * 768 + h * 64 + d] = f2b(val);
    }
  }
}

// ---------------------------------------------------------------- launcher
extern "C" void kernel_launch(void* const* d_in, const int* in_sizes, int n_in,
                              void* d_out, int out_size, void* d_ws, size_t ws_size,
                              hipStream_t stream) {
  const float* x = (const float*)d_in[0];
  const float* qkvw = (const float*)d_in[1];
  const float* projw = (const float*)d_in[2];
  const float* projb = (const float*)d_in[3];
  const float* btab = (const float*)d_in[4];
  float* out = (float*)d_out;
  char* ws = (char*)d_ws;

  // workspace layout (bytes)
  u16* xb = (u16*)(ws);                    // 8192*768 bf16 = 12,582,912 B
  u16* wqkvT = (u16*)(ws + 12582912);      // 2304*768 bf16 =  3,538,944 B
  u16* wprojT = (u16*)(ws + 16121856);     //  768*768 bf16 =  1,179,648 B
  u16* qbuf = (u16*)(ws + 17301504);       // 12,582,912 B
  u16* kbuf = (u16*)(ws + 29884416);       // 12,582,912 B
  u16* vTbuf = (u16*)(ws + 42467328);      // 12,582,912 B
  u16* biasg = (u16*)(ws + 55050240);      // 12*4096*2 =      98,304 B
  u16* ao = xb;  // reuse: xb dead after QKV GEMM (stream-serialized)

  cast_x_kernel<<<6144, 256, 0, stream>>>(x, xb, 8192 * 768 / 4);
  transpose_cast<<<dim3(72, 24), 256, 0, stream>>>(qkvw, wqkvT, 768, 2304);
  transpose_cast<<<dim3(24, 24), 256, 0, stream>>>(projw, wprojT, 768, 768);
  gather_bias<<<192, 256, 0, stream>>>(btab, biasg);

  gemm128<0><<<dim3(18, 64), 256, 0, stream>>>(xb, wqkvT, 768, qbuf, kbuf,
                                               vTbuf, nullptr, nullptr, 0);

  attn_kernel<<<768, 512, 0, stream>>>(qbuf, kbuf, vTbuf, biasg, ao);

  gemm128<1><<<dim3(6, 64), 256, 0, stream>>>(ao, wprojT, 768, nullptr, nullptr,
                                              nullptr, projb, out, 768);
}

// Round 9
// 173.953 us; speedup vs baseline: 1.0228x; 1.0228x over previous
//
#include <hip/hip_runtime.h>

typedef unsigned short u16;
typedef __attribute__((ext_vector_type(8))) short bf16x8;
typedef __attribute__((ext_vector_type(4))) short s16x4;
typedef __attribute__((ext_vector_type(4))) float f32x4;

#define MFMA(a, b, c) __builtin_amdgcn_mfma_f32_16x16x32_bf16(a, b, c, 0, 0, 0)

// global -> LDS direct copy, 16 B per lane. LDS dest must be wave-uniform base
// (HW adds lane*16). Global source is per-lane.
#define GLDS16(gp, lp)                                                        \
  __builtin_amdgcn_global_load_lds(                                          \
      (__attribute__((address_space(1))) void*)(void*)(gp),                  \
      (__attribute__((address_space(3))) void*)(lp), 16, 0, 0)

__device__ __forceinline__ u16 f2b(float f) {
  union { float f; unsigned u; } x; x.f = f;
  unsigned r = x.u + 0x7fffu + ((x.u >> 16) & 1u);
  return (u16)(r >> 16);
}
__device__ __forceinline__ float b2f(u16 v) {
  union { unsigned u; float f; } x; x.u = ((unsigned)v) << 16;
  return x.f;
}

// Stage a [32*NPASS rows][64 cols] bf16 tile into LDS with XOR-swizzled SOURCE
// slots so a swizzled ds_read recovers linear data. (256-thread version.)
template <int NPASS>
__device__ __forceinline__ void stage64(const u16* __restrict__ src, int ld,
                                        u16* lds, int t) {
  int wave = t >> 6;
#pragma unroll
  for (int p = 0; p < NPASS; ++p) {
    int row = p * 32 + (t >> 3);
    int ss = (t & 7) ^ (row & 7);
    const u16* g = src + row * ld + ss * 8;
    GLDS16(g, lds + (p * 2048 + wave * 512));
  }
}

// 512-thread version: one pass stages a full 64x64 bf16 tile.
__device__ __forceinline__ void stage512(const u16* __restrict__ src, int ld,
                                         u16* lds, int t) {
  int row = t >> 3;
  int ss = (t & 7) ^ (row & 7);
  GLDS16(src + row * ld + ss * 8, lds + (t >> 6) * 512);
}

// read one MFMA fragment (8 consecutive bf16) at [row][slot*8], swizzle-corrected
__device__ __forceinline__ bf16x8 ldsfrag(const u16* base, int row, int slot) {
  int byte = row * 128 + (((slot) ^ (row & 7)) << 4);
  return *(const bf16x8*)((const char*)base + byte);
}

// ---------------------------------------------------------------- prep kernels
__global__ void cast_x_kernel(const float* __restrict__ in, u16* __restrict__ out,
                              int n4) {
  int i = blockIdx.x * blockDim.x + threadIdx.x;
  if (i < n4) {
    float4 v = ((const float4*)in)[i];
    ushort4 o;
    o.x = f2b(v.x); o.y = f2b(v.y); o.z = f2b(v.z); o.w = f2b(v.w);
    ((ushort4*)out)[i] = o;
  }
}

// out[(c, r)] = bf16(in[(r, c)]); in is (R, Ccols) fp32 row-major.
__global__ void transpose_cast(const float* __restrict__ in, u16* __restrict__ out,
                               int R, int Ccols) {
  __shared__ u16 tile[32][33];
  int c0 = blockIdx.x * 32, r0 = blockIdx.y * 32;
  int tx = threadIdx.x & 31, ty = threadIdx.x >> 5;
#pragma unroll
  for (int rr = ty; rr < 32; rr += 8)
    tile[rr][tx] = f2b(in[(size_t)(r0 + rr) * Ccols + c0 + tx]);
  __syncthreads();
#pragma unroll
  for (int rr = ty; rr < 32; rr += 8)
    out[(size_t)(c0 + rr) * R + r0 + tx] = tile[tx][rr];
}

// bias_table (65025,12) fp32 -> per-head contiguous bf16 [12][4096] (3969 used)
// PRE-SCALED by log2(e): softmax runs in exp2 domain.
__global__ void gather_bias(const float* __restrict__ btab, u16* __restrict__ out) {
  int i = blockIdx.x * 256 + threadIdx.x;  // [0, 12*4096)
  int h = i >> 12, r = i & 4095;
  out[i] = (r < 3969) ? f2b(btab[r * 12 + h] * 1.44269504f) : (u16)0;
}

// ---------------------------------------------------------------- GEMM 128x128
// C = A(M,K) @ BT(N,K)^T, bf16 inputs, fp32 accum.
template <int EPI>
__global__ __launch_bounds__(256, 2) void gemm128(
    const u16* __restrict__ A, const u16* __restrict__ BT, int K,
    u16* __restrict__ qo, u16* __restrict__ ko, u16* __restrict__ vo,
    const float* __restrict__ pb, float* __restrict__ out, int Nld) {
  __shared__ __align__(16) u16 As[128 * 64];
  __shared__ __align__(16) u16 Bs[128 * 64];
  const int t = threadIdx.x;
  const int wave = t >> 6, lane = t & 63;
  const int wr = wave >> 1, wc = wave & 1;
  const int tileRow = blockIdx.y * 128, tileCol = blockIdx.x * 128;
  const u16* Ab = A + (size_t)tileRow * K;
  const u16* Bb = BT + (size_t)tileCol * K;

  f32x4 acc[4][4] = {};
  for (int k0 = 0; k0 < K; k0 += 64) {
    __syncthreads();
    stage64<4>(Ab + k0, K, As, t);
    stage64<4>(Bb + k0, K, Bs, t);
    __syncthreads();
#pragma unroll
    for (int kk = 0; kk < 2; ++kk) {
      bf16x8 af[4], bfr[4];
#pragma unroll
      for (int m = 0; m < 4; ++m)
        af[m] = ldsfrag(As, wr * 64 + m * 16 + (lane & 15), kk * 4 + (lane >> 4));
#pragma unroll
      for (int n = 0; n < 4; ++n)
        bfr[n] = ldsfrag(Bs, wc * 64 + n * 16 + (lane & 15), kk * 4 + (lane >> 4));
#pragma unroll
      for (int m = 0; m < 4; ++m)
#pragma unroll
        for (int n = 0; n < 4; ++n)
          acc[m][n] = MFMA(af[m], bfr[n], acc[m][n]);
    }
  }

#pragma unroll
  for (int m = 0; m < 4; ++m) {
#pragma unroll
    for (int n = 0; n < 4; ++n) {
#pragma unroll
      for (int r = 0; r < 4; ++r) {
        int row = tileRow + wr * 64 + m * 16 + (lane >> 4) * 4 + r;
        int col = tileCol + wc * 64 + n * 16 + (lane & 15);
        float val = acc[m][n][r];
        if (EPI == 0) {
          int which = col / 768;
          int c = col - which * 768;
          int hh = c >> 6, d = c & 63;
          int bb = row >> 10, nn = row & 1023;
          size_t bhnd = ((size_t)(bb * 12 + hh) * 1024 + nn) * 64 + d;
          if (which == 0)
            qo[bhnd] = f2b(val * 0.18033688f);  // 0.125 * log2(e)
          else if (which == 1)
            ko[bhnd] = f2b(val);
          else
            vo[((size_t)(bb * 12 + hh) * 64 + d) * 1024 + nn] = f2b(val);
        } else {
          out[(size_t)row * Nld + col] = val + pb[col];
        }
      }
    }
  }
}

// ---------------------------------------------------------------- attention
// 8-wave blocks (QBLK=128), swapped-QK softmax in exp2 domain, KVBLK=128:
// one stage (2x 64-key halves of K and V) feeds TWO compute passes -> barrier
// events halve and wave dephasing amortizes softmax latency chains. R7/R8
// showed sync flavor is irrelevant -> plain __syncthreads.
// grid: 768 flat (XCD-chunked: one batch per XCD); block: 512 (8 waves).
__global__ __launch_bounds__(512, 6) void attn_kernel(
    const u16* __restrict__ qm, const u16* __restrict__ kmat,
    const u16* __restrict__ vT, const u16* __restrict__ bias_g,
    u16* __restrict__ ao) {
  __shared__ __align__(16) u16 bias_s[35 * 64];
  __shared__ __align__(16) u16 Ks[2][64 * 64];
  __shared__ __align__(16) u16 Vs[2][64 * 64];
  __shared__ __align__(16) u16 Ps[8][1024];  // per-wave 16x64 P tile

  const int t = threadIdx.x;
  const int wave = t >> 6, lane = t & 63;
  const int g = lane >> 4, q = lane & 15;
  // XCD-chunked swizzle: id%8 = XCD, one batch (96 blocks) per XCD.
  const int id = blockIdx.x;
  const int sw = (id & 7) * 96 + (id >> 3);
  const int qt = sw & 7, h = (sw >> 3) % 12, b = sw / 96;
  const int bh = b * 12 + h;

  const u16* kb0 = kmat + (size_t)bh * 1024 * 64;
  const u16* vb0 = vT + (size_t)bh * 64 * 1024;

  // prologue: bias rows dy in [4qt, 4qt+34] (63 cols, stride-64 pad)
  if (t < 280) {
    const u16* bg = bias_g + h * 4096 + qt * 4 * 63;
    GLDS16(bg + (t >> 3) * 63 + (t & 7) * 8, bias_s + (t >> 6) * 512);
  }

  // Q fragments in registers (q pre-scaled by 0.125*log2e); B-operand: col = q
  const u16* qb = qm + ((size_t)bh * 1024 + qt * 128) * 64;
  bf16x8 qf[2];
#pragma unroll
  for (int kk = 0; kk < 2; ++kk)
    qf[kk] = *(const bf16x8*)(qb + (wave * 16 + q) * 64 + kk * 32 + g * 8);

  f32x4 o[4] = {};
  float mrun = -1e30f, lrun = 0.f;

  // this lane's softmax q-row (for S^T layout)
  const int iq = qt * 128 + wave * 16 + q;
  const int ylq = (wave * 16 + q) >> 5;  // local yi (0..3): yi = 4qt + ylq
  const int xi = iq & 31;

  for (int kt8 = 0; kt8 < 8; ++kt8) {
    __syncthreads();  // all waves done reading both halves (prev round)
    stage512(kb0 + kt8 * 8192, 64, Ks[0], t);
    stage512(kb0 + kt8 * 8192 + 4096, 64, Ks[1], t);
    stage512(vb0 + kt8 * 128, 1024, Vs[0], t);
    stage512(vb0 + kt8 * 128 + 64, 1024, Vs[1], t);
    __syncthreads();  // 128-key tile landed

#pragma unroll
    for (int half = 0; half < 2; ++half) {
      const int kt = kt8 * 2 + half;
      const u16* Kc = Ks[half];
      const u16* Vc = Vs[half];

      // S^T = K @ Q^T: s[n][r] = S[key = n*16 + g*4 + r][qrow = q]
      f32x4 s[4] = {};
#pragma unroll
      for (int kk = 0; kk < 2; ++kk) {
#pragma unroll
        for (int n = 0; n < 4; ++n) {
          bf16x8 kf = ldsfrag(Kc, n * 16 + q, kk * 4 + g);
          s[n] = MFMA(kf, qf[kk], s[n]);
        }
      }

      // + relative position bias (exp2-domain): key j = kt*64 + n*16 + g*4 + r
#pragma unroll
      for (int n = 0; n < 4; ++n) {
        int xj0 = (n & 1) * 16 + g * 4;
        int ldy = ylq - kt * 2 - (n >> 1) + 31;
        int bse = ldy * 64 + (xi - xj0 + 31);
#pragma unroll
        for (int r = 0; r < 4; ++r) s[n][r] += b2f(bias_s[bse - r]);
      }

      // row max: 15 local fmax + 2 cross-group shuffles
      float mx = fmaxf(fmaxf(fmaxf(s[0][0], s[0][1]), fmaxf(s[0][2], s[0][3])),
                       fmaxf(fmaxf(s[1][0], s[1][1]), fmaxf(s[1][2], s[1][3])));
      mx = fmaxf(mx,
                 fmaxf(fmaxf(fmaxf(s[2][0], s[2][1]), fmaxf(s[2][2], s[2][3])),
                       fmaxf(fmaxf(s[3][0], s[3][1]), fmaxf(s[3][2], s[3][3]))));
      mx = fmaxf(mx, __shfl_xor(mx, 16));
      mx = fmaxf(mx, __shfl_xor(mx, 32));

      // defer-max (8 nats = 11.54 bits)
      if (__any(mx > mrun + 11.5f)) {
        float mn = fmaxf(mrun, mx);
        float al = __builtin_amdgcn_exp2f(mrun - mn);
        mrun = mn;
        lrun *= al;
#pragma unroll
        for (int r = 0; r < 4; ++r) {
          float ar = __shfl(al, (lane & 48) | (g * 4 + r));
#pragma unroll
          for (int nd = 0; nd < 4; ++nd) o[nd][r] *= ar;
        }
      }

      // exp2 + sum
      float ps = 0.f;
#pragma unroll
      for (int n = 0; n < 4; ++n) {
#pragma unroll
        for (int r = 0; r < 4; ++r) {
          float p = __builtin_amdgcn_exp2f(s[n][r] - mrun);
          s[n][r] = p;
          ps += p;
        }
      }
      ps += __shfl_xor(ps, 16);
      ps += __shfl_xor(ps, 32);
      lrun += ps;

      // P -> wave-local LDS (row q, keys n*16+g*4..+3), swizzled, short4 stores
#pragma unroll
      for (int n = 0; n < 4; ++n) {
        int byte = (q * 128 + n * 32 + g * 8) ^ ((q & 7) << 4);
        union { unsigned u[2]; s16x4 v; } w;
        w.u[0] = (unsigned)f2b(s[n][0]) | ((unsigned)f2b(s[n][1]) << 16);
        w.u[1] = (unsigned)f2b(s[n][2]) | ((unsigned)f2b(s[n][3]) << 16);
        *(s16x4*)((char*)Ps[wave] + byte) = w.v;
      }
      __builtin_amdgcn_sched_barrier(0);  // fence: P stores before PV reads

      // O += P @ V (A-frag: row q; Vs holds V^T: rows = d, cols = key)
#pragma unroll
      for (int kk = 0; kk < 2; ++kk) {
        bf16x8 pf = ldsfrag(Ps[wave], q, kk * 4 + g);
#pragma unroll
        for (int nd = 0; nd < 4; ++nd) {
          bf16x8 vf = ldsfrag(Vc, nd * 16 + q, kk * 4 + g);
          o[nd] = MFMA(pf, vf, o[nd]);
        }
      }
    }
  }

  // epilogue: redistribute 1/l to output rows, O/l -> (B, N, nh*hd) bf16
  float lr[4];
#pragma unroll
  for (int r = 0; r < 4; ++r)
    lr[r] = __shfl(lrun, (lane & 48) | (g * 4 + r));
#pragma unroll
  for (int nd = 0; nd < 4; ++nd) {
#pragma unroll
    for (int r = 0; r < 4; ++r) {
      int i = qt * 128 + wave * 16 + g * 4 + r;
      int d = nd * 16 + q;
      float val = o[nd][r] / lr[r];
      ao[((size_t)b * 1024 + i) * 768 + h * 64 + d] = f2b(val);
    }
  }
}

// ---------------------------------------------------------------- launcher
extern "C" void kernel_launch(void* const* d_in, const int* in_sizes, int n_in,
                              void* d_out, int out_size, void* d_ws, size_t ws_size,
                              hipStream_t stream) {
  const float* x = (const float*)d_in[0];
  const float* qkvw = (const float*)d_in[1];
  const float* projw = (const float*)d_in[2];
  const float* projb = (const float*)d_in[3];
  const float* btab = (const float*)d_in[4];
  float* out = (float*)d_out;
  char* ws = (char*)d_ws;

  // workspace layout (bytes)
  u16* xb = (u16*)(ws);                    // 8192*768 bf16 = 12,582,912 B
  u16* wqkvT = (u16*)(ws + 12582912);      // 2304*768 bf16 =  3,538,944 B
  u16* wprojT = (u16*)(ws + 16121856);     //  768*768 bf16 =  1,179,648 B
  u16* qbuf = (u16*)(ws + 17301504);       // 12,582,912 B
  u16* kbuf = (u16*)(ws + 29884416);       // 12,582,912 B
  u16* vTbuf = (u16*)(ws + 42467328);      // 12,582,912 B
  u16* biasg = (u16*)(ws + 55050240);      // 12*4096*2 =      98,304 B
  u16* ao = xb;  // reuse: xb dead after QKV GEMM (stream-serialized)

  cast_x_kernel<<<6144, 256, 0, stream>>>(x, xb, 8192 * 768 / 4);
  transpose_cast<<<dim3(72, 24), 256, 0, stream>>>(qkvw, wqkvT, 768, 2304);
  transpose_cast<<<dim3(24, 24), 256, 0, stream>>>(projw, wprojT, 768, 768);
  gather_bias<<<192, 256, 0, stream>>>(btab, biasg);

  gemm128<0><<<dim3(18, 64), 256, 0, stream>>>(xb, wqkvT, 768, qbuf, kbuf,
                                               vTbuf, nullptr, nullptr, 0);

  attn_kernel<<<768, 512, 0, stream>>>(qbuf, kbuf, vTbuf, biasg, ao);

  gemm128<1><<<dim3(6, 64), 256, 0, stream>>>(ao, wprojT, 768, nullptr, nullptr,
                                              nullptr, projb, out, 768);
}